// Round 7
// baseline (239.517 us; speedup 1.0000x reference)
//
#include <hip/hip_runtime.h>
#include <math.h>

#define BB 2
#define NN 512
#define DD 128
#define HH 8
#define DKK 16
#define TR 32            // tile rows
#define NT (NN / TR)     // 16 tiles per (b,n)

// direct global->LDS DMA (dest = wave-uniform base + lane*size)
#define GL_LDS16(gp, lp)                                                     \
    __builtin_amdgcn_global_load_lds(                                        \
        (const __attribute__((address_space(1))) void*)(gp),                 \
        (__attribute__((address_space(3))) void*)(lp), 16, 0, 0)
#define GL_LDS4(gp, lp)                                                      \
    __builtin_amdgcn_global_load_lds(                                        \
        (const __attribute__((address_space(1))) void*)(gp),                 \
        (__attribute__((address_space(3))) void*)(lp), 4, 0, 0)

// ---------------- Kernel 1: QKV projection + W_egT staging ----------------
__global__ __launch_bounds__(128)
void qkv_kernel(const float* __restrict__ n_in,
                const float* __restrict__ W_qkv,
                const float* __restrict__ W_g,
                const float* __restrict__ W_e,
                float* __restrict__ Qw, float* __restrict__ Kw,
                float* __restrict__ Vw, float* __restrict__ WegT)
{
    const int bid = blockIdx.x;
    if (bid >= BB * NN) {                    // 16 trailing blocks: WegT[col][d]
        const int col = bid - BB * NN;       // 0..15
        const int t = threadIdx.x;           // 0..127
        WegT[col * DD + t] = (col < 8) ? W_e[t * HH + col]
                                       : W_g[t * HH + (col - 8)];
        return;
    }
    __shared__ float nrow[DD];
    const int bn = bid;
    const int b  = bn >> 9;
    const int nr = bn & 511;
    const int t  = threadIdx.x;
    nrow[t] = n_in[(size_t)bn * DD + t];
    __syncthreads();
    const int h = t >> 4, dk = t & 15;
    const size_t dst = ((size_t)(b * HH + h) * NN + nr) * DKK + dk;
    float accq = 0.f, acck = 0.f, accv = 0.f;
    #pragma unroll 8
    for (int d = 0; d < DD; ++d) {
        const float nv = nrow[d];
        const float* wr = W_qkv + (size_t)d * 3 * DD;
        accq += nv * wr[t];
        acck += nv * wr[t + 128];
        accv += nv * wr[t + 256];
    }
    Qw[dst] = accq;
    Kw[dst] = acck;
    Vw[dst] = accv;
}

// ---------------- Kernel 1b: QKc = clamp(Q K^T * scale) ----------------
__global__ __launch_bounds__(256)
void qk_kernel(const float* __restrict__ Qw,
               const float* __restrict__ Kw,
               float* __restrict__ QKc)      // [B*N][H][NN]... stored [b][h][q][m]-style below
{
    __shared__ __align__(16) float4 Kl[NN * 4];   // 32KB  [m][4]
    __shared__ __align__(16) float4 Ql[32 * 4];   // 2KB   [qr][4]

    const int bid = blockIdx.x;
    const int qt  = bid & 15;
    const int h   = (bid >> 4) & 7;
    const int b   = bid >> 7;
    const int t   = threadIdx.x;

    const float4* __restrict__ kb =
        (const float4*)Kw + ((size_t)(b * HH + h) * NN) * 4;
    #pragma unroll
    for (int j = 0; j < 8; ++j) Kl[j * 256 + t] = kb[j * 256 + t];
    if (t < 128)
        Ql[t] = ((const float4*)Qw)[((size_t)(b * HH + h) * NN + qt * 32) * 4 + t];
    __syncthreads();

    const int qr = t >> 3;        // 0..31
    const int mq = t & 7;         // 0..7 -> 64 m's each
    const float4 q0 = Ql[qr * 4 + 0];
    const float4 q1 = Ql[qr * 4 + 1];
    const float4 q2 = Ql[qr * 4 + 2];
    const float4 q3 = Ql[qr * 4 + 3];

    float4* __restrict__ out4 =
        (float4*)QKc + (((size_t)(b * NN + qt * 32 + qr) * HH + h) * NN) / 4;

    #pragma unroll 1
    for (int c = 0; c < 16; ++c) {
        float4 r;
        float* rp = (float*)&r;
        #pragma unroll
        for (int i = 0; i < 4; ++i) {
            const int m = mq * 64 + c * 4 + i;
            const float4 k0 = Kl[m * 4 + 0];
            const float4 k1 = Kl[m * 4 + 1];
            const float4 k2 = Kl[m * 4 + 2];
            const float4 k3 = Kl[m * 4 + 3];
            float s = q0.x*k0.x + q0.y*k0.y + q0.z*k0.z + q0.w*k0.w
                    + q1.x*k1.x + q1.y*k1.y + q1.z*k1.z + q1.w*k1.w
                    + q2.x*k2.x + q2.y*k2.y + q2.z*k2.z + q2.w*k2.w
                    + q3.x*k3.x + q3.y*k3.y + q3.z*k3.z + q3.w*k3.w;
            s *= 0.25f;
            rp[i] = fminf(5.f, fmaxf(-5.f, s));
        }
        out4[mq * 16 + c] = r;
    }
}

// ---------------- Kernel 2: fused E/G + (+QKc) + e_out ----------------
// One block per (b,n), 512 threads = 8 waves. W in registers (d-sliced per
// lane, shuffle-reduced) -> each e-row read ONCE per wave from LDS.
__global__ __launch_bounds__(512, 4)
void eg_kernel(const float* __restrict__ e,
               const float* __restrict__ WegT,
               const float* __restrict__ O_e,
               const float* __restrict__ QKc,
               float* __restrict__ EGw,     // [B*N][H][NN] _E (per bn: [h][m])
               float* __restrict__ Gfull,   // [B*N][H]
               float* __restrict__ e_out)
{
    __shared__ __align__(16) float4 buf4[2][TR * 32];   // 2 x 16KB e-tiles
    __shared__ __align__(16) float  qkcL[2][HH * TR];   // 2 x 1KB [h][m]
    __shared__ __align__(16) float  ET2[TR][HH];        // 1KB [m][h]

    const int t    = threadIdx.x;
    const int bn   = blockIdx.x;
    const int wq   = t >> 6;          // wave 0..7
    const int lane = t & 63;
    const int r    = lane & 7;        // row-within-group
    const int sp   = lane >> 3;       // d-slice 0..7 (16 floats each)
    const int c0   = 2 * wq;          // this wave's WegT column pair
    const int c4o  = t & 31;          // e_out float4 column
    const int m0   = t >> 5;          // e_out row base 0..15

    // ---- W slices into registers (32 VGPR) ----
    const float4* __restrict__ WegT4 = (const float4*)WegT;
    float4 wA[4], wB[4];
    #pragma unroll
    for (int k = 0; k < 4; ++k) {
        wA[k] = WegT4[(c0    ) * 32 + sp * 4 + k];
        wB[k] = WegT4[(c0 + 1) * 32 + sp * 4 + k];
    }
    // O_e column cache (32 VGPR)
    float4 oe[8];
    #pragma unroll
    for (int h = 0; h < 8; ++h)
        oe[h] = ((const float4*)O_e)[h * 32 + c4o];

    const float4* __restrict__ e4 = (const float4*)e + (size_t)bn * NN * 32;
    const float*  __restrict__ qkb = QKc + (size_t)bn * HH * NN;

    // staging macro: e-tile (2 x GL16/thread, pre-swizzled source) + qkc tile
    #define STAGE(tile, pb)                                                   \
    {                                                                         \
        _Pragma("unroll")                                                     \
        for (int j = 0; j < 2; ++j) {                                         \
            const int q = j * 512 + t;                                        \
            const int m_ = q >> 5, x_ = q & 31;                               \
            GL_LDS16(e4 + (size_t)(tile) * 1024 + m_ * 32 + (x_ ^ m_),        \
                     &buf4[pb][j * 512 + (t & ~63)]);                         \
        }                                                                     \
        if (t < 256) {                                                        \
            GL_LDS4(qkb + (size_t)(t >> 5) * NN + (tile) * TR + (t & 31),     \
                    &qkcL[pb][t & ~63]);                                      \
        }                                                                     \
    }

    // ---- Phase A body ----
    #define PHASE_A(tt, pb)                                                   \
    {                                                                         \
        const float4* __restrict__ bp = buf4[pb];                             \
        _Pragma("unroll")                                                     \
        for (int g = 0; g < 4; ++g) {                                         \
            const int m = g * 8 + r;                                          \
            float a0 = 0.f, a1 = 0.f;                                         \
            _Pragma("unroll")                                                 \
            for (int k = 0; k < 4; ++k) {                                     \
                const float4 ev = bp[m * 32 + ((4 * sp + k) ^ m)];            \
                a0 += ev.x*wA[k].x + ev.y*wA[k].y + ev.z*wA[k].z + ev.w*wA[k].w; \
                a1 += ev.x*wB[k].x + ev.y*wB[k].y + ev.z*wB[k].z + ev.w*wB[k].w; \
            }                                                                 \
            a0 += __shfl_xor(a0, 8, 64);  a1 += __shfl_xor(a1, 8, 64);        \
            a0 += __shfl_xor(a0, 16, 64); a1 += __shfl_xor(a1, 16, 64);       \
            a0 += __shfl_xor(a0, 32, 64); a1 += __shfl_xor(a1, 32, 64);       \
            if (wq < 4) {                                                     \
                if (lane < 8) {                                               \
                    const float v0 = a0 + qkcL[pb][(c0    ) * TR + m];        \
                    const float v1 = a1 + qkcL[pb][(c0 + 1) * TR + m];        \
                    *(float2*)&ET2[m][c0] = float2{v0, v1};                   \
                    EGw[((size_t)bn * HH + c0    ) * NN + (tt) * TR + m] = v0; \
                    EGw[((size_t)bn * HH + c0 + 1) * NN + (tt) * TR + m] = v1; \
                }                                                             \
            } else {                                                          \
                ga0 += 1.f / (1.f + __expf(-a0));                             \
                ga1 += 1.f / (1.f + __expf(-a1));                             \
            }                                                                 \
        }                                                                     \
    }

    // ---- Phase C body: e_out tile from ET2 ----
    #define PHASE_C(tt)                                                       \
    {                                                                         \
        float4* __restrict__ out4 =                                           \
            (float4*)e_out + ((size_t)bn * NN + (tt) * TR) * 32;              \
        _Pragma("unroll")                                                     \
        for (int it = 0; it < 2; ++it) {                                      \
            const int m = m0 + it * 16;                                       \
            const float4 elo = *(const float4*)&ET2[m][0];                    \
            const float4 ehi = *(const float4*)&ET2[m][4];                    \
            float4 rr;                                                        \
            rr.x = elo.x*oe[0].x + elo.y*oe[1].x + elo.z*oe[2].x + elo.w*oe[3].x \
                 + ehi.x*oe[4].x + ehi.y*oe[5].x + ehi.z*oe[6].x + ehi.w*oe[7].x; \
            rr.y = elo.x*oe[0].y + elo.y*oe[1].y + elo.z*oe[2].y + elo.w*oe[3].y \
                 + ehi.x*oe[4].y + ehi.y*oe[5].y + ehi.z*oe[6].y + ehi.w*oe[7].y; \
            rr.z = elo.x*oe[0].z + elo.y*oe[1].z + elo.z*oe[2].z + elo.w*oe[3].z \
                 + ehi.x*oe[4].z + ehi.y*oe[5].z + ehi.z*oe[6].z + ehi.w*oe[7].z; \
            rr.w = elo.x*oe[0].w + elo.y*oe[1].w + elo.z*oe[2].w + elo.w*oe[3].w \
                 + ehi.x*oe[4].w + ehi.y*oe[5].w + ehi.z*oe[6].w + ehi.w*oe[7].w; \
            out4[m * 32 + c4o] = rr;                                          \
        }                                                                     \
    }

    float ga0 = 0.f, ga1 = 0.f;

    // prologue: stage tile 0, full drain
    STAGE(0, 0);
    asm volatile("s_waitcnt vmcnt(0)" ::: "memory");
    __builtin_amdgcn_s_barrier();

    int p = 0;
    #pragma unroll 1
    for (int tt = 0; tt < NT - 1; ++tt) {
        STAGE(tt + 1, p ^ 1);
        asm volatile("s_waitcnt vmcnt(4)" ::: "memory");
        __builtin_amdgcn_s_barrier();       // buf[p], qkcL[p] ready; ET2 free
        PHASE_A(tt, p);
        asm volatile("s_waitcnt lgkmcnt(0)" ::: "memory");
        __builtin_amdgcn_s_barrier();       // ET2 final
        PHASE_C(tt);
        p ^= 1;
    }
    // epilogue tile
    asm volatile("s_waitcnt vmcnt(2)" ::: "memory");
    __builtin_amdgcn_s_barrier();
    PHASE_A(NT - 1, p);
    asm volatile("s_waitcnt lgkmcnt(0)" ::: "memory");
    __builtin_amdgcn_s_barrier();
    PHASE_C(NT - 1);

    // ---- final G reduction (waves 4..7: heads c0-8, c0-7) ----
    if (wq >= 4) {
        ga0 += __shfl_xor(ga0, 1, 64);  ga1 += __shfl_xor(ga1, 1, 64);
        ga0 += __shfl_xor(ga0, 2, 64);  ga1 += __shfl_xor(ga1, 2, 64);
        ga0 += __shfl_xor(ga0, 4, 64);  ga1 += __shfl_xor(ga1, 4, 64);
        if (lane == 0) {
            Gfull[(size_t)bn * HH + (c0 - 8)] = ga0;
            Gfull[(size_t)bn * HH + (c0 - 7)] = ga1;
        }
    }
    #undef STAGE
    #undef PHASE_A
    #undef PHASE_C
}

// ---------------- Kernel 3: softmax + AV + n_out ----------------
__global__ __launch_bounds__(256)
void attn_kernel(const float* __restrict__ EGw,
                 const float* __restrict__ Gfull,
                 const float* __restrict__ Vw,
                 const float* __restrict__ O_n,
                 float* __restrict__ n_out)
{
    __shared__ __align__(16) float ET[HH * NN];   // 16KB
    __shared__ __align__(16) float vout[DD];
    __shared__ float dc[HH];

    const int t    = threadIdx.x;
    const int bn   = blockIdx.x;
    const int b    = bn >> 9;
    const int wq   = t >> 6;
    const int lane = t & 63;

    const float4* __restrict__ eg4 = (const float4*)(EGw + (size_t)bn * HH * NN);
    float4* et4 = (float4*)ET;
    #pragma unroll
    for (int i = t; i < HH * NN / 4; i += 256) et4[i] = eg4[i];
    if (t < HH) dc[t] = log1pf(Gfull[(size_t)bn * HH + t]);
    __syncthreads();

    #pragma unroll 1
    for (int hw = 0; hw < 2; ++hw) {
        const int h = wq * 2 + hw;
        float vals[8];
        float rmax = -1e30f;
        #pragma unroll
        for (int k = 0; k < 8; ++k) {
            vals[k] = ET[h * NN + k * 64 + lane];
            rmax = fmaxf(rmax, vals[k]);
        }
        #pragma unroll
        for (int off = 32; off >= 1; off >>= 1)
            rmax = fmaxf(rmax, __shfl_xor(rmax, off, 64));
        float sum = 0.f;
        #pragma unroll
        for (int k = 0; k < 8; ++k) sum += __expf(vals[k] - rmax);
        #pragma unroll
        for (int off = 32; off >= 1; off >>= 1)
            sum += __shfl_xor(sum, off, 64);
        const float factor = dc[h] / sum;

        const int ddx = lane & 15, mg = lane >> 4;
        const float* __restrict__ vb = Vw + ((size_t)(b * HH + h) * NN) * DKK;
        float av = 0.f;
        #pragma unroll 4
        for (int m = mg; m < NN; m += 4) {
            const float p = __expf(ET[h * NN + m] - rmax);
            av += p * vb[m * DKK + ddx];
        }
        av += __shfl_xor(av, 16, 64);
        av += __shfl_xor(av, 32, 64);
        if (mg == 0) vout[h * DKK + ddx] = av * factor;
    }
    __syncthreads();

    if (t < DD) {
        float a3 = 0.f;
        #pragma unroll 4
        for (int d = 0; d < DD; ++d) a3 += vout[d] * O_n[d * DD + t];
        n_out[(size_t)bn * DD + t] = a3;
    }
}

extern "C" void kernel_launch(void* const* d_in, const int* in_sizes, int n_in,
                              void* d_out, int out_size, void* d_ws, size_t ws_size,
                              hipStream_t stream)
{
    const float* n_ptr = (const float*)d_in[0];
    const float* e     = (const float*)d_in[1];
    const float* W_qkv = (const float*)d_in[2];
    const float* O_n   = (const float*)d_in[3];
    const float* W_g   = (const float*)d_in[4];
    const float* W_e   = (const float*)d_in[5];
    const float* O_e   = (const float*)d_in[6];

    float* n_out = (float*)d_out;
    float* e_out = n_out + (size_t)BB * NN * DD;

    float* Qw    = (float*)d_ws;                          // 3 x 0.5MB
    float* Kw    = Qw + (size_t)BB * HH * NN * DKK;
    float* Vw    = Kw + (size_t)BB * HH * NN * DKK;
    float* EGw   = Vw + (size_t)BB * HH * NN * DKK;       // 16.8MB
    float* QKc   = EGw + (size_t)BB * HH * NN * NN;       // 16.8MB
    float* Gfull = QKc + (size_t)BB * HH * NN * NN;       // 32KB
    float* WegT  = Gfull + (size_t)BB * NN * HH;          // 8KB

    qkv_kernel<<<BB * NN + 16, 128, 0, stream>>>(n_ptr, W_qkv, W_g, W_e,
                                                 Qw, Kw, Vw, WegT);
    qk_kernel<<<BB * HH * 16, 256, 0, stream>>>(Qw, Kw, QKc);
    eg_kernel<<<BB * NN, 512, 0, stream>>>(e, WegT, O_e, QKc,
                                           EGw, Gfull, e_out);
    attn_kernel<<<BB * NN, 256, 0, stream>>>(EGw, Gfull, Vw, O_n, n_out);
}